// Round 17
// baseline (114.000 us; speedup 1.0000x reference)
//
#include <hip/hip_runtime.h>

// SAGEConv: h[50000,64] f32, src/dst[800000] int32, W[128,64] f32, b[64] f32
// out = concat(h, mean_{in-edges}(h[src])) @ W + b
//
// R17 = R14 (best measured, 113.4us) + one change: cursorG padded to one
// cursor per 64B cache line. R14's 77k atomic-returns hit 49 lines (16
// cursors/line) -> ~1568 serialized memory-side RMWs per line (~20-30us).
// Padding spreads them: 98 increments/line, lines parallel across channels.
// (R16's fp8 gather was perf-neutral -> gather is issue/latency-bound, not
// byte/line-bound; reverted to bf16 for 5x error margin.)
// Lessons: read-side reduction only (R6); dense contiguous pairs > sparse
// fixed-slot (R15); R9 scatter > LDS sort (R12); MFMA for K=128 MLP (R14).

#define IN_FEAT 64
#define KB_SHIFT 6            // 64 nodes per bucket
#define BKN 64
#define CAP 2048              // max pairs per bucket (mean 1024)
#define KMAX 1024             // supports n_nodes <= 65536
#define CSTRIDE 16            // cursorG stride: one int cursor per 64B line
#define AP 136                // A/Wt row pad (shorts): 272B rows, 16B-aligned

typedef __attribute__((ext_vector_type(8))) short short8;   // 8 bf16 = 4 VGPR
typedef __attribute__((ext_vector_type(4))) float f32x4;

__device__ __forceinline__ unsigned short f2bf(float f) {
    unsigned u = __float_as_uint(f);
    return (unsigned short)((u + 0x7FFFu + ((u >> 16) & 1u)) >> 16);
}
__device__ __forceinline__ float bf2f(unsigned short s) {
    return __uint_as_float(((unsigned)s) << 16);
}

// ---- k1: blocks [0,conv_tiles): h->bf16 ; rest: bucket the edges (R9) ------
__global__ __launch_bounds__(512) void sage_prep(
    const float* __restrict__ h, const int* __restrict__ src,
    const int* __restrict__ dst,
    unsigned short* __restrict__ hb, unsigned* __restrict__ pairs,
    int* __restrict__ cursorG,           // padded: cursor k at [k*CSTRIDE]
    int n4, int n_edges, int conv_tiles, int K)
{
    __shared__ int cnt[KMAX];
    __shared__ int base[KMAX];
    int t = (int)threadIdx.x;

    if ((int)blockIdx.x < conv_tiles) {
        int tb = blockIdx.x * 8192;
        #pragma unroll
        for (int i = 0; i < 16; ++i) {
            int idx = tb + t + i * 512;            // float4 index
            if (idx < n4) {
                float4 v = ((const float4*)h)[idx];
                ushort4 r;
                r.x = f2bf(v.x); r.y = f2bf(v.y);
                r.z = f2bf(v.z); r.w = f2bf(v.w);
                ((ushort4*)hb)[idx] = r;
            }
        }
    } else {
        for (int k = t; k < K; k += 512) cnt[k] = 0;
        __syncthreads();
        int tb = ((int)blockIdx.x - conv_tiles) * 8192;
        int kb[16]; unsigned pk[16]; int rk[16];
        #pragma unroll 4
        for (int i = 0; i < 16; ++i) {
            int e = tb + t + i * 512;
            kb[i] = -1;
            if (e < n_edges) {
                int d = dst[e], s = src[e];
                int k = d >> KB_SHIFT;
                kb[i] = k;
                pk[i] = ((unsigned)s << KB_SHIFT) | (unsigned)(d & (BKN - 1));
                rk[i] = atomicAdd(&cnt[k], 1);     // rank within (tile,bucket)
            }
        }
        __syncthreads();
        for (int k = t; k < K; k += 512) {
            int c = cnt[k];
            base[k] = c ? atomicAdd(&cursorG[k * CSTRIDE], c) : 0;
        }
        __syncthreads();
        #pragma unroll 4
        for (int i = 0; i < 16; ++i) {
            if (kb[i] >= 0) {
                int pos = base[kb[i]] + rk[i];
                if (pos < CAP)                      // safety clamp
                    pairs[((size_t)kb[i] << 11) + pos] = pk[i];
            }
        }
    }
}

// ---- k2: local CSR + gather-mean + MFMA output -----------------------------
// One block (1024 thr, 16 waves) per 64-node bucket; LDS ~44KB, 2 blocks/CU.
__global__ __launch_bounds__(1024, 8) void sage_fused(
    const unsigned short* __restrict__ hb,
    const unsigned* __restrict__ pairs,
    const int* __restrict__ cursorG,
    const float* __restrict__ W,     // [128,64] row-major f32
    const float* __restrict__ bias,
    float* __restrict__ out,
    int n_nodes)
{
    __shared__ unsigned short Wt[64][AP];   // bf16 W^T: Wt[n][k], 17.4 KB
    __shared__ unsigned short A[BKN][AP];   // [self(0:64) | hn(64:128)], 17.4 KB
    __shared__ float bsh[64];
    __shared__ int   list[CAP];             // 8 KB
    __shared__ int   cnt[BKN];
    __shared__ int   rs[BKN + 1];

    const int t = (int)threadIdx.x;
    const int b   = (int)blockIdx.x;
    const int nlo = b << KB_SHIFT;

    // stage Wt (bf16 transpose of W): 8192 elems, 8 per thread
    #pragma unroll
    for (int i = 0; i < 8; ++i) {
        int idx = t + i * 1024;              // idx = k*64 + n
        int k = idx >> 6, n = idx & 63;
        Wt[n][k] = f2bf(W[idx]);
    }
    // stage A self half from hb: 64 rows x 64 shorts, ushort4 per thread
    {
        int nl = t >> 4, c4 = (t & 15) * 4;
        if (nlo + nl < n_nodes)
            *(ushort4*)&A[nl][c4] =
                *(const ushort4*)(hb + ((size_t)(nlo + nl) << 6) + c4);
    }
    if (t < 64) { bsh[t] = bias[t]; cnt[t] = 0; }
    __syncthreads();

    int m = cursorG[b * CSTRIDE]; if (m > CAP) m = CAP;
    const unsigned* pb = pairs + ((size_t)b << 11);

    // A-phase: single-atomic-pass local CSR (2 pairs per thread)
    unsigned lp[2]; int lr[2];
    #pragma unroll
    for (int i = 0; i < 2; ++i) {
        int idx = t + i * 1024;
        lr[i] = -1;
        if (idx < m) {
            lp[i] = pb[idx];
            lr[i] = atomicAdd(&cnt[lp[i] & (BKN - 1)], 1);
        }
    }
    __syncthreads();
    if (t < 64) {            // wave 0 scans the 64 counters
        int v = cnt[t];
        int incl = v;
        #pragma unroll
        for (int off = 1; off < 64; off <<= 1) {
            int x = __shfl_up(incl, off);
            if (t >= off) incl += x;
        }
        rs[t] = incl - v;
        if (t == 63) rs[64] = incl;
    }
    __syncthreads();
    #pragma unroll
    for (int i = 0; i < 2; ++i)
        if (lr[i] >= 0)
            list[rs[lp[i] & (BKN - 1)] + lr[i]] = (int)(lp[i] >> KB_SHIFT);
    __syncthreads();

    const int w    = t >> 6;         // wave 0..15
    const int lane = t & 63;
    const int sub  = lane >> 4;
    const int q    = lane & 15;

    // B-phase: gather — wave w owns nodes w*4..w*4+3, mean -> A[nl][64+...]
    #pragma unroll
    for (int i = 0; i < 4; ++i) {
        int nl = w * 4 + i;
        int n  = nlo + nl;
        if (n >= n_nodes) break;               // wave-uniform
        int beg = rs[nl], end = rs[nl + 1];
        float4 acc = make_float4(0.f, 0.f, 0.f, 0.f);
        int e = beg + sub;
        for (; e + 12 < end; e += 16) {        // 4 edges in flight per lane
            int s0 = list[e], s1 = list[e + 4], s2 = list[e + 8], s3 = list[e + 12];
            const ushort4 u0 = *(const ushort4*)(hb + ((size_t)s0 << 6) + q * 4);
            const ushort4 u1 = *(const ushort4*)(hb + ((size_t)s1 << 6) + q * 4);
            const ushort4 u2 = *(const ushort4*)(hb + ((size_t)s2 << 6) + q * 4);
            const ushort4 u3 = *(const ushort4*)(hb + ((size_t)s3 << 6) + q * 4);
            acc.x += (bf2f(u0.x) + bf2f(u1.x)) + (bf2f(u2.x) + bf2f(u3.x));
            acc.y += (bf2f(u0.y) + bf2f(u1.y)) + (bf2f(u2.y) + bf2f(u3.y));
            acc.z += (bf2f(u0.z) + bf2f(u1.z)) + (bf2f(u2.z) + bf2f(u3.z));
            acc.w += (bf2f(u0.w) + bf2f(u1.w)) + (bf2f(u2.w) + bf2f(u3.w));
        }
        for (; e + 4 < end; e += 8) {
            int s0 = list[e], s1 = list[e + 4];
            const ushort4 u0 = *(const ushort4*)(hb + ((size_t)s0 << 6) + q * 4);
            const ushort4 u1 = *(const ushort4*)(hb + ((size_t)s1 << 6) + q * 4);
            acc.x += bf2f(u0.x) + bf2f(u1.x);
            acc.y += bf2f(u0.y) + bf2f(u1.y);
            acc.z += bf2f(u0.z) + bf2f(u1.z);
            acc.w += bf2f(u0.w) + bf2f(u1.w);
        }
        if (e < end) {
            int s0 = list[e];
            const ushort4 u0 = *(const ushort4*)(hb + ((size_t)s0 << 6) + q * 4);
            acc.x += bf2f(u0.x); acc.y += bf2f(u0.y);
            acc.z += bf2f(u0.z); acc.w += bf2f(u0.w);
        }
        #pragma unroll
        for (int mm = 16; mm < 64; mm <<= 1) {
            acc.x += __shfl_xor(acc.x, mm);
            acc.y += __shfl_xor(acc.y, mm);
            acc.z += __shfl_xor(acc.z, mm);
            acc.w += __shfl_xor(acc.w, mm);
        }
        int deg = end - beg;
        float inv = (deg > 0) ? (1.0f / (float)deg) : 0.f;
        if (sub == 0) {
            ushort4 r;
            r.x = f2bf(acc.x * inv); r.y = f2bf(acc.y * inv);
            r.z = f2bf(acc.z * inv); r.w = f2bf(acc.w * inv);
            *(ushort4*)&A[nl][64 + q * 4] = r;
        }
    }
    __syncthreads();   // A's hn half is written by all waves; MFMA reads all

    // C-phase: MFMA — wave w computes C-tile (mt = w>>2, nt = w&3)
    {
        const int mt = w >> 2, nt = w & 3;
        const int quad = lane >> 4, l16 = lane & 15;
        f32x4 acc;
        float bv = bsh[nt * 16 + l16];
        acc[0] = bv; acc[1] = bv; acc[2] = bv; acc[3] = bv;
        #pragma unroll
        for (int ks = 0; ks < 4; ++ks) {
            const short8 aF = *(const short8*)&A[mt * 16 + l16][ks * 32 + quad * 8];
            const short8 bF = *(const short8*)&Wt[nt * 16 + l16][ks * 32 + quad * 8];
            acc = __builtin_amdgcn_mfma_f32_16x16x32_bf16(aF, bF, acc, 0, 0, 0);
        }
        #pragma unroll
        for (int r = 0; r < 4; ++r) {
            int row = nlo + mt * 16 + quad * 4 + r;
            if (row < n_nodes)
                out[((size_t)row << 6) + nt * 16 + l16] = acc[r];
        }
    }
}

extern "C" void kernel_launch(void* const* d_in, const int* in_sizes, int n_in,
                              void* d_out, int out_size, void* d_ws, size_t ws_size,
                              hipStream_t stream) {
    const float* h   = (const float*)d_in[0];
    const int*   src = (const int*)d_in[1];
    const int*   dst = (const int*)d_in[2];
    const float* W   = (const float*)d_in[3];
    const float* b   = (const float*)d_in[4];
    float* out = (float*)d_out;

    const int n_nodes = in_sizes[0] / IN_FEAT;
    const int n_edges = in_sizes[1];
    const int K  = (n_nodes + BKN - 1) >> KB_SHIFT;    // 782
    const int n4 = n_nodes * (IN_FEAT / 4);            // 800000 float4s

    // ws: hb[N*64 ushort] | pairs[K*CAP u32] | cursorG[K*CSTRIDE]
    unsigned short* hb = (unsigned short*)d_ws;
    unsigned* pairs    = (unsigned*)(hb + (size_t)n_nodes * IN_FEAT);
    int* cursorG       = (int*)(pairs + (size_t)K * CAP);

    hipMemsetAsync(cursorG, 0, (size_t)K * CSTRIDE * sizeof(int), stream);

    const int conv_tiles   = (n4 + 8191) / 8192;       // 98
    const int bucket_tiles = (n_edges + 8191) / 8192;  // 98
    sage_prep<<<conv_tiles + bucket_tiles, 512, 0, stream>>>(
        h, src, dst, hb, pairs, cursorG, n4, n_edges, conv_tiles, K);
    sage_fused<<<K, 1024, 0, stream>>>(hb, pairs, cursorG, W, b, out, n_nodes);
}